// Round 15
// baseline (80.985 us; speedup 1.0000x reference)
//
#include <hip/hip_runtime.h>
#include <hip/hip_bf16.h>

// PolymorphicSNN: reference collapses to
//   out[:, :256]     = heaviside(x @ W_lin.T + b_lin - 1.0)
//   out[:, 256:8448] = 0    (spk_mode == 0 identically since reg_out in {0,1})
//
// R2..R14 finding: ANY wave mixing compute/loads with the bulk store stream
// caps at ~4.8 TB/s (59-67 us across occupancy/prefetch/role/store-type
// variants); pure-store rocclr fill sustains 6.9 TB/s on this buffer.
// This round: dispatch-level purity, 2 dispatches.
//   1. fill+transpose kernel: 8192 blocks stream 268 MB of zeros (pure
//      store regime); 256 extra blocks transpose W -> WT (tiny).
//   2. GEMM-only kernel: 256 blocks x 4 waves, 8 rows/wave (WT read once
//      per 8 rows -> 256 MB L2), depth-2 W prefetch, x from LDS, spike
//      stores only. No bulk stores in any GEMM wave.
// Decisive either way: ~54 us confirms the mixing penalty; ~70 us proves
// the strided fill region itself caps near 5 TB/s (then 59 us ~= roofline).

#define SNN_B 8192
#define SNN_N 256
#define SNN_P 32
#define SNN_ROW (SNN_N * (SNN_P + 1))   // 8448 floats per output row
#define BLK_ROWS 32                     // batch rows per GEMM block (8/wave)

// ---- Dispatch 1: pure fill (8192 blocks) + W transpose (256 blocks) ----
__global__ __launch_bounds__(256) void fill_wt_kernel(
    const float* __restrict__ W, float* __restrict__ WT,
    float* __restrict__ out)
{
    const int b   = blockIdx.x;
    const int tid = threadIdx.x;
    if (b < SNN_B) {
        // Zero one row's fill region: 8192 floats = 2048 float4.
        float4* o4 = reinterpret_cast<float4*>(out + (size_t)b * SNN_ROW + SNN_N);
        const float4 z = make_float4(0.f, 0.f, 0.f, 0.f);
#pragma unroll
        for (int i = 0; i < 8; ++i) o4[tid + i * 256] = z;
    } else {
        // W transpose: WT[k][n] = W[n][k]; coalesced writes.
        const int o = (b - SNN_B) * 256 + tid;   // 0..65535
        const int k = o >> 8, n = o & 255;
        WT[o] = W[n * SNN_N + k];
    }
}

// ---- Dispatch 2: GEMM + spikes only (no bulk stores) ----
__global__ __launch_bounds__(256) void polysnn_gemm_kernel(
    const float* __restrict__ x,      // [B, N]
    const float* __restrict__ W,      // [N, N] original (borderline recheck only)
    const float* __restrict__ WT,     // [N, N] transposed: WT[k][n]
    const float* __restrict__ bias,   // [N]
    float* __restrict__ out)          // [B, 8448]
{
    __shared__ float xs[BLK_ROWS][SNN_N];

    const int tid  = threadIdx.x;
    const int lane = tid & 63;
    const int wave = tid >> 6;
    const int row0 = blockIdx.x * BLK_ROWS;

    // Stage 32 x-rows (32 KB): 2048 float4, 8 per thread.
    {
        const float4* x4  = reinterpret_cast<const float4*>(x + (size_t)row0 * SNN_N);
        float4*       xsw = reinterpret_cast<float4*>(&xs[0][0]);
#pragma unroll
        for (int i = 0; i < 8; ++i) xsw[tid + i * 256] = x4[tid + i * 256];
    }
    __syncthreads();

    // Wave owns rows grow0..+7; lane owns cols 4*lane..4*lane+3.
    const int grow0 = row0 + wave * 8;
    const float4* wt4 = reinterpret_cast<const float4*>(WT);   // [k][64 float4]
    const float4* xs4 = reinterpret_cast<const float4*>(&xs[0][0]);
    const int xbase = wave * 8 * 64;   // float4 index of wave's first row

    float acc[8][4];
#pragma unroll
    for (int r = 0; r < 8; ++r)
#pragma unroll
        for (int c = 0; c < 4; ++c) acc[r][c] = 0.0f;

    // Depth-2 W prefetch (x comes from LDS: lgkmcnt, decoupled from vmcnt).
    float4 wA0 = wt4[(0 * 4 + 0) * 64 + lane];
    float4 wA1 = wt4[(0 * 4 + 1) * 64 + lane];
    float4 wA2 = wt4[(0 * 4 + 2) * 64 + lane];
    float4 wA3 = wt4[(0 * 4 + 3) * 64 + lane];
    float4 wB0 = wt4[(1 * 4 + 0) * 64 + lane];
    float4 wB1 = wt4[(1 * 4 + 1) * 64 + lane];
    float4 wB2 = wt4[(1 * 4 + 2) * 64 + lane];
    float4 wB3 = wt4[(1 * 4 + 3) * 64 + lane];

#define SNN_FMA_ITER(W0, W1, W2, W3, IT)                                 \
    do {                                                                 \
        _Pragma("unroll")                                                \
        for (int r = 0; r < 8; ++r) {                                    \
            const float4 xr = xs4[xbase + r * 64 + (IT)];                \
            acc[r][0] = fmaf(xr.x, W0.x, acc[r][0]);                     \
            acc[r][1] = fmaf(xr.x, W0.y, acc[r][1]);                     \
            acc[r][2] = fmaf(xr.x, W0.z, acc[r][2]);                     \
            acc[r][3] = fmaf(xr.x, W0.w, acc[r][3]);                     \
            acc[r][0] = fmaf(xr.y, W1.x, acc[r][0]);                     \
            acc[r][1] = fmaf(xr.y, W1.y, acc[r][1]);                     \
            acc[r][2] = fmaf(xr.y, W1.z, acc[r][2]);                     \
            acc[r][3] = fmaf(xr.y, W1.w, acc[r][3]);                     \
            acc[r][0] = fmaf(xr.z, W2.x, acc[r][0]);                     \
            acc[r][1] = fmaf(xr.z, W2.y, acc[r][1]);                     \
            acc[r][2] = fmaf(xr.z, W2.z, acc[r][2]);                     \
            acc[r][3] = fmaf(xr.z, W2.w, acc[r][3]);                     \
            acc[r][0] = fmaf(xr.w, W3.x, acc[r][0]);                     \
            acc[r][1] = fmaf(xr.w, W3.y, acc[r][1]);                     \
            acc[r][2] = fmaf(xr.w, W3.z, acc[r][2]);                     \
            acc[r][3] = fmaf(xr.w, W3.w, acc[r][3]);                     \
        }                                                                \
    } while (0)

    for (int body = 0; body < 32; ++body) {
        const int i0  = body * 2;
        const int ipA = (i0 + 2) & 63;     // wrap: last body's prefetch redundant
        const int ipB = (i0 + 3) & 63;

        float4 tA0 = wt4[(ipA * 4 + 0) * 64 + lane];
        float4 tA1 = wt4[(ipA * 4 + 1) * 64 + lane];
        float4 tA2 = wt4[(ipA * 4 + 2) * 64 + lane];
        float4 tA3 = wt4[(ipA * 4 + 3) * 64 + lane];
        float4 tB0 = wt4[(ipB * 4 + 0) * 64 + lane];
        float4 tB1 = wt4[(ipB * 4 + 1) * 64 + lane];
        float4 tB2 = wt4[(ipB * 4 + 2) * 64 + lane];
        float4 tB3 = wt4[(ipB * 4 + 3) * 64 + lane];

        SNN_FMA_ITER(wA0, wA1, wA2, wA3, i0);
        SNN_FMA_ITER(wB0, wB1, wB2, wB3, i0 + 1);

        wA0 = tA0; wA1 = tA1; wA2 = tA2; wA3 = tA3;
        wB0 = tB0; wB1 = tB1; wB2 = tB2; wB3 = tB3;
    }
#undef SNN_FMA_ITER

    // ---- epilogue: bias, threshold, rare f64 recheck, coalesced spike store ----
    const float4 bb = reinterpret_cast<const float4*>(bias)[lane];
#pragma unroll
    for (int r = 0; r < 8; ++r) {
        float h[4] = {acc[r][0] + bb.x, acc[r][1] + bb.y,
                      acc[r][2] + bb.z, acc[r][3] + bb.w};
        float s[4];
#pragma unroll
        for (int c = 0; c < 4; ++c) {
            if (__builtin_expect(fabsf(h[c] - 1.0f) < 1e-3f, 0)) {
                // Borderline (f32 accum error <= ~6e-5 << 1e-3): f64 recheck.
                const int n = 4 * lane + c;
                double a = (double)bias[n];
                const float* wr = W + (size_t)n * SNN_N;
                for (int k = 0; k < SNN_N; ++k)
                    a += (double)wr[k] * (double)xs[wave * 8 + r][k];
                s[c] = (a > 1.0) ? 1.0f : 0.0f;
            } else {
                s[c] = (h[c] > 1.0f) ? 1.0f : 0.0f;
            }
        }
        *reinterpret_cast<float4*>(out + (size_t)(grow0 + r) * SNN_ROW + (lane << 2))
            = make_float4(s[0], s[1], s[2], s[3]);
    }
}

// ---- Fallback (ws too small): round-2 monolithic kernel (69 us, absmax 0) ----
__global__ __launch_bounds__(256) void polysnn_mono_kernel(
    const float* __restrict__ x, const float* __restrict__ W,
    const float* __restrict__ bias, float* __restrict__ out)
{
    __shared__ float xs[8][SNN_N];
    const int tid = threadIdx.x;
    const int row0 = blockIdx.x * 8;
    {
        const float4* x4  = reinterpret_cast<const float4*>(x + (size_t)row0 * SNN_N);
        float4*       xsw = reinterpret_cast<float4*>(&xs[0][0]);
        xsw[tid] = x4[tid]; xsw[tid + 256] = x4[tid + 256];
    }
    __syncthreads();
    const float4 zz = make_float4(0.f, 0.f, 0.f, 0.f);
#pragma unroll
    for (int r = 0; r < 8; ++r) {
        float4* o4 = reinterpret_cast<float4*>(out + (size_t)(row0 + r) * SNN_ROW + SNN_N);
#pragma unroll
        for (int i = 0; i < 8; ++i) o4[tid + i * 256] = zz;
    }
    const int n = tid;
    float acc[8];
#pragma unroll
    for (int r = 0; r < 8; ++r) acc[r] = 0.0f;
    const float4* w4  = reinterpret_cast<const float4*>(W + (size_t)n * SNN_N);
    const float4* xs4 = reinterpret_cast<const float4*>(&xs[0][0]);
#pragma unroll 4
    for (int k4 = 0; k4 < SNN_N / 4; ++k4) {
        const float4 w = w4[k4];
#pragma unroll
        for (int r = 0; r < 8; ++r) {
            const float4 xr = xs4[r * 64 + k4];
            acc[r] = fmaf(w.x, xr.x, acc[r]); acc[r] = fmaf(w.y, xr.y, acc[r]);
            acc[r] = fmaf(w.z, xr.z, acc[r]); acc[r] = fmaf(w.w, xr.w, acc[r]);
        }
    }
    const float bn = bias[n];
#pragma unroll
    for (int r = 0; r < 8; ++r) {
        const float h = acc[r] + bn;
        float spike;
        if (__builtin_expect(fabsf(h - 1.0f) < 1e-3f, 0)) {
            double a = (double)bn;
            const float* wr = W + (size_t)n * SNN_N;
            for (int k = 0; k < SNN_N; ++k) a += (double)wr[k] * (double)xs[r][k];
            spike = (a > 1.0) ? 1.0f : 0.0f;
        } else spike = (h > 1.0f) ? 1.0f : 0.0f;
        out[(size_t)(row0 + r) * SNN_ROW + n] = spike;
    }
}

extern "C" void kernel_launch(void* const* d_in, const int* in_sizes, int n_in,
                              void* d_out, int out_size, void* d_ws, size_t ws_size,
                              hipStream_t stream) {
    const float* x     = (const float*)d_in[0];
    const float* W_lin = (const float*)d_in[1];
    const float* b_lin = (const float*)d_in[2];
    // d_in[3] (W_sel) and d_in[4] (b_sel) are dead: spk_mode == 0 identically.
    float* out = (float*)d_out;

    if (ws_size >= (size_t)SNN_N * SNN_N * sizeof(float)) {
        float* WT = (float*)d_ws;
        // Dispatch 1: pure-regime fill (8192 blocks) + WT transpose (256 blocks).
        fill_wt_kernel<<<SNN_B + 256, 256, 0, stream>>>(W_lin, WT, out);
        // Dispatch 2: GEMM + spikes only.
        polysnn_gemm_kernel<<<SNN_B / BLK_ROWS, 256, 0, stream>>>(x, W_lin, WT, b_lin, out);
    } else {
        polysnn_mono_kernel<<<SNN_B / 8, 256, 0, stream>>>(x, W_lin, b_lin, out);
    }
}